// Round 1
// baseline (877.229 us; speedup 1.0000x reference)
//
#include <hip/hip_runtime.h>
#include <math.h>

// Problem constants: B=8, C=256, H=W=128
#define PIX 16384                       // H*W
#define TSZ ((size_t)33554432)          // 8*256*16384 elements per tensor

typedef __attribute__((ext_vector_type(8))) short  short8;   // 8 x bf16 (4 VGPRs)
typedef __attribute__((ext_vector_type(4))) float  float4v;
typedef __attribute__((ext_vector_type(4))) unsigned int uint4v;

__device__ __forceinline__ unsigned short f2bf(float x) {
  unsigned int u = __float_as_uint(x);
  u += 0x7fffu + ((u >> 16) & 1u);      // round-to-nearest-even
  return (unsigned short)(u >> 16);
}
__device__ __forceinline__ float bf2f(unsigned short h) {
  return __uint_as_float(((unsigned int)h) << 16);
}

// ---------------------------------------------------------------------------
// Kernel 0: convert the four 256x256 weight matrices to bf16.
// Conv order: 0=FF(wf), 1=GG(wg), 2=EE(we), 3=HH(wh)
// ---------------------------------------------------------------------------
__global__ __launch_bounds__(256) void k_prep(const float* __restrict__ we,
                                              const float* __restrict__ wf,
                                              const float* __restrict__ wg,
                                              const float* __restrict__ wh,
                                              unsigned short* __restrict__ wbf) {
  int idx = blockIdx.x * 256 + threadIdx.x;      // 0 .. 262143
  int which = idx >> 16, off = idx & 65535;
  const float* src = (which == 0) ? wf : (which == 1) ? wg : (which == 2) ? we : wh;
  wbf[idx] = f2bf(src[off]);
}

// ---------------------------------------------------------------------------
// Kernel 1: 7x7 patch stats (zero-padded box sums), normalization, adain.
// One block per (b, c, 16-row strip). Processes BACK then FRONT so back's
// mean/std can be carried in LDS for adain.
// Writes 4 bf16 tensors channel-major into xcm[tensor][b][c][p]:
//   0 = front_norm (FF input), 1 = back_norm (GG input),
//   2 = adain      (EE input), 3 = back cast (HH input)
// ---------------------------------------------------------------------------
__global__ __launch_bounds__(256) void k_stats(const float* __restrict__ front,
                                               const float* __restrict__ back,
                                               unsigned short* __restrict__ xcm) {
  int blk = blockIdx.x;
  int s   = blk & 7;            // strip (16 rows)
  int c   = (blk >> 3) & 255;
  int b   = blk >> 11;
  int t   = threadIdx.x;
  int r0  = s * 16;

  // fp32 work buffers: stride 129 breaks bank-power-of-2; bf16 out buffers
  // stride 136 (16B-aligned rows for b128 copy-out, <=4-way write conflicts).
  __shared__ float xs[22 * 129];
  __shared__ float vs[16 * 129];
  __shared__ float vs2[16 * 129];
  __shared__ __align__(16) unsigned short mb[16 * 136];
  __shared__ __align__(16) unsigned short sb[16 * 136];
  __shared__ __align__(16) unsigned short ob0[16 * 136];
  __shared__ __align__(16) unsigned short ob1[16 * 136];

  size_t planeOff = ((size_t)(b * 256 + c)) * PIX;

  #pragma unroll 1
  for (int phase = 0; phase < 2; ++phase) {     // 0 = back, 1 = front
    const float* src = (phase == 0 ? back : front) + planeOff;
    __syncthreads();                             // protect xs reuse
    // load 22 rows (3-halo each side, zero outside [0,128)) x 128 cols
    #pragma unroll
    for (int i = 0; i < 11; ++i) {
      int idx = t + i * 256;                     // 2816 = 22*128 exact
      int l = idx >> 7, col = idx & 127;
      int g = r0 - 3 + l;
      float v = 0.f;
      if (g >= 0 && g < 128) v = src[g * 128 + col];
      xs[l * 129 + col] = v;
    }
    __syncthreads();
    // vertical 7-tap sliding box sums of x and x^2
    {
      int col = t & 127;
      int rg  = (t >> 7) * 8;                    // 8 output rows per thread
      float sm = 0.f, s2 = 0.f;
      #pragma unroll
      for (int j = 0; j < 7; ++j) { float v = xs[(rg + j) * 129 + col]; sm += v; s2 += v * v; }
      vs[rg * 129 + col] = sm; vs2[rg * 129 + col] = s2;
      #pragma unroll
      for (int o = 1; o < 8; ++o) {
        float vn = xs[(rg + o + 6) * 129 + col];
        float vo = xs[(rg + o - 1) * 129 + col];
        sm += vn - vo; s2 += vn * vn - vo * vo;
        vs[(rg + o) * 129 + col] = sm; vs2[(rg + o) * 129 + col] = s2;
      }
    }
    __syncthreads();
    // horizontal 7-tap sliding + finalize (mean, unbiased var, norm, adain)
    {
      int r  = t & 15;
      int c0 = (t >> 4) * 8;                     // 8 output cols per thread
      float sm = 0.f, s2 = 0.f;
      #pragma unroll
      for (int d = -3; d <= 3; ++d) {
        int cc = c0 + d;
        if (cc >= 0 && cc < 128) { sm += vs[r * 129 + cc]; s2 += vs2[r * 129 + cc]; }
      }
      #pragma unroll
      for (int o = 0; o < 8; ++o) {
        int cc = c0 + o;
        float mean = sm * (1.f / 49.f);
        float var  = (s2 - sm * mean) * (1.f / 48.f);   // (s2 - s^2/49)/48
        var = var > 0.f ? var : 0.f;
        float sd = sqrtf(var);
        float x  = xs[(r + 3) * 129 + cc];
        float nrm = (x - mean) / (sd + 1e-8f);
        int oi = r * 136 + cc;
        if (phase == 0) {
          ob0[oi] = f2bf(nrm);                   // back_norm
          ob1[oi] = f2bf(x);                     // back (bf16 cast)
          mb[oi]  = f2bf(mean);
          sb[oi]  = f2bf(sd);
        } else {
          ob0[oi] = f2bf(nrm);                   // front_norm
          float ada = nrm * bf2f(sb[oi]) + bf2f(mb[oi]);   // no eps on y_std
          ob1[oi] = f2bf(ada);                   // adain
        }
        int cr = cc - 3, ca = cc + 4;
        if (cr >= 0)  { sm -= vs[r * 129 + cr]; s2 -= vs2[r * 129 + cr]; }
        if (ca < 128) { sm += vs[r * 129 + ca]; s2 += vs2[r * 129 + ca]; }
      }
    }
    __syncthreads();
    // coalesced copy-out: 256 threads x 8 bf16 = 16x128 tile, 16B stores
    {
      int r  = t >> 4;
      int cc = (t & 15) * 8;
      uint4v v0 = *(const uint4v*)(ob0 + r * 136 + cc);
      uint4v v1 = *(const uint4v*)(ob1 + r * 136 + cc);
      size_t gb = planeOff + (size_t)(r0 + r) * 128 + cc;
      int tn0 = (phase == 0) ? 1 : 0;
      int tn1 = (phase == 0) ? 3 : 2;
      *(uint4v*)(xcm + (size_t)tn0 * TSZ + gb) = v0;
      *(uint4v*)(xcm + (size_t)tn1 * TSZ + gb) = v1;
    }
  }
}

// ---------------------------------------------------------------------------
// Kernel 2: four fused conv1x1 GEMMs per 64-pixel tile via bf16 MFMA.
// WG = 256 threads = 4 waves, m-split (each wave 64 output channels).
// Fragment layouts (gfx950 16x16x32 bf16, HW-verified in learn_hip):
//   A: A[m=lane&15][k=quad*8+j]   B: B[k=quad*8+j][n=lane&15]
//   D: row(m)=quad*4+reg, col(n)=lane&15
// B-fragments are gathered with 8 scalar ushort loads (channel-major source);
// each instruction is 32B-contiguous per quad and L1/L2 resident.
// ---------------------------------------------------------------------------
__device__ __forceinline__ void gemm_tile(const unsigned short* __restrict__ X,
                                          const unsigned short* __restrict__ Wm,
                                          int mbase, int lane, int p0,
                                          float4v acc[4][4]) {
  int col = lane & 15;
  int q   = lane >> 4;
  #pragma unroll
  for (int in = 0; in < 4; ++in)
    #pragma unroll
    for (int im = 0; im < 4; ++im)
      acc[in][im] = (float4v){0.f, 0.f, 0.f, 0.f};
  #pragma unroll 2
  for (int k0 = 0; k0 < 256; k0 += 32) {
    int kq = k0 + q * 8;
    short8 af[4];
    #pragma unroll
    for (int im = 0; im < 4; ++im)
      af[im] = *(const short8*)(Wm + (mbase + im * 16 + col) * 256 + kq);
    short8 bfr[4];
    #pragma unroll
    for (int in = 0; in < 4; ++in) {
      const unsigned short* xb = X + (size_t)kq * PIX + (p0 + in * 16 + col);
      union { short8 v; unsigned int u[4]; } bu;
      #pragma unroll
      for (int i = 0; i < 4; ++i) {
        unsigned int lo = xb[(size_t)(2 * i) * PIX];
        unsigned int hi = xb[(size_t)(2 * i + 1) * PIX];
        bu.u[i] = lo | (hi << 16);
      }
      bfr[in] = bu.v;
    }
    #pragma unroll
    for (int in = 0; in < 4; ++in)
      #pragma unroll
      for (int im = 0; im < 4; ++im)
        acc[in][im] = __builtin_amdgcn_mfma_f32_16x16x32_bf16(af[im], bfr[in], acc[in][im], 0, 0, 0);
  }
}

__global__ __launch_bounds__(256, 2) void k_gemm(const unsigned short* __restrict__ xcm,
                                                 const unsigned short* __restrict__ wbf,
                                                 const float* __restrict__ bFF,
                                                 const float* __restrict__ bGG,
                                                 const float* __restrict__ bEE,
                                                 const float* __restrict__ bHH,
                                                 unsigned short* __restrict__ eecm,
                                                 unsigned short* __restrict__ hhcm,
                                                 float* __restrict__ Sout) {
  int blk  = blockIdx.x;
  int b    = blk >> 8;
  int p0   = (blk & 255) * 64;
  int t    = threadIdx.x;
  int wv   = t >> 6;
  int lane = t & 63;
  int col  = lane & 15;
  int q    = lane >> 4;
  int mbase = wv * 64;

  __shared__ float sred[3 * 64];       // dot, |F|^2, |G|^2 per pixel
  if (t < 192) sred[t] = 0.f;
  __syncthreads();

  const unsigned short* Xb = xcm + (size_t)b * (256 * PIX);

  float4v aF[4][4], aG[4][4];

  // FF = wf * front_norm + bf ; GG = wg * back_norm + bg
  gemm_tile(Xb + 0 * TSZ, wbf + 0 * 65536, mbase, lane, p0, aF);
  gemm_tile(Xb + 1 * TSZ, wbf + 1 * 65536, mbase, lane, p0, aG);
  #pragma unroll
  for (int im = 0; im < 4; ++im) {
    float4v bvF = *(const float4v*)(bFF + mbase + im * 16 + q * 4);
    float4v bvG = *(const float4v*)(bGG + mbase + im * 16 + q * 4);
    #pragma unroll
    for (int in = 0; in < 4; ++in) { aF[in][im] += bvF; aG[in][im] += bvG; }
  }
  // cosine partials: lane-local over 16 m's, then quad shuffle, then LDS
  #pragma unroll
  for (int in = 0; in < 4; ++in) {
    float d = 0.f, nf = 0.f, ng = 0.f;
    #pragma unroll
    for (int im = 0; im < 4; ++im)
      #pragma unroll
      for (int r = 0; r < 4; ++r) {
        float f = aF[in][im][r], g = aG[in][im][r];
        d += f * g; nf += f * f; ng += g * g;
      }
    d  += __shfl_xor(d, 16);  d  += __shfl_xor(d, 32);
    nf += __shfl_xor(nf, 16); nf += __shfl_xor(nf, 32);
    ng += __shfl_xor(ng, 16); ng += __shfl_xor(ng, 32);
    if (lane < 16) {
      atomicAdd(&sred[0 * 64 + in * 16 + lane], d);
      atomicAdd(&sred[1 * 64 + in * 16 + lane], nf);
      atomicAdd(&sred[2 * 64 + in * 16 + lane], ng);
    }
  }
  // EE = we * adain + be  -> store bf16 channel-major
  gemm_tile(Xb + 2 * TSZ, wbf + 2 * 65536, mbase, lane, p0, aF);
  #pragma unroll
  for (int im = 0; im < 4; ++im) {
    float4v bv = *(const float4v*)(bEE + mbase + im * 16 + q * 4);
    #pragma unroll
    for (int in = 0; in < 4; ++in)
      #pragma unroll
      for (int r = 0; r < 4; ++r) {
        int m = mbase + im * 16 + q * 4 + r;
        eecm[((size_t)(b * 256 + m)) * PIX + p0 + in * 16 + col] = f2bf(aF[in][im][r] + bv[r]);
      }
  }
  // HH = wh * back + bh
  gemm_tile(Xb + 3 * TSZ, wbf + 3 * 65536, mbase, lane, p0, aG);
  #pragma unroll
  for (int im = 0; im < 4; ++im) {
    float4v bv = *(const float4v*)(bHH + mbase + im * 16 + q * 4);
    #pragma unroll
    for (int in = 0; in < 4; ++in)
      #pragma unroll
      for (int r = 0; r < 4; ++r) {
        int m = mbase + im * 16 + q * 4 + r;
        hhcm[((size_t)(b * 256 + m)) * PIX + p0 + in * 16 + col] = f2bf(aG[in][im][r] + bv[r]);
      }
  }
  __syncthreads();
  if (t < 64) {
    float d = sred[t], nf = sred[64 + t], ng = sred[128 + t];
    Sout[(size_t)b * PIX + p0 + t] = d / (sqrtf(nf) * sqrtf(ng));
  }
}

// ---------------------------------------------------------------------------
// Kernel 3: per-batch min/max of S (one block per batch)
// ---------------------------------------------------------------------------
__global__ __launch_bounds__(256) void k_minmax(const float* __restrict__ S,
                                                float* __restrict__ mm) {
  int b = blockIdx.x, t = threadIdx.x;
  const float* sp = S + (size_t)b * PIX;
  float mn = 3.0e38f, mx = -3.0e38f;
  for (int i = t; i < PIX; i += 256) { float v = sp[i]; mn = fminf(mn, v); mx = fmaxf(mx, v); }
  #pragma unroll
  for (int o = 32; o >= 1; o >>= 1) {
    mn = fminf(mn, __shfl_xor(mn, o));
    mx = fmaxf(mx, __shfl_xor(mx, o));
  }
  __shared__ float smn[4], smx[4];
  if ((t & 63) == 0) { smn[t >> 6] = mn; smx[t >> 6] = mx; }
  __syncthreads();
  if (t == 0) {
    mn = fminf(fminf(smn[0], smn[1]), fminf(smn[2], smn[3]));
    mx = fmaxf(fmaxf(smx[0], smx[1]), fmaxf(smx[2], smx[3]));
    mm[b * 2] = mn; mm[b * 2 + 1] = mx;
  }
}

// ---------------------------------------------------------------------------
// Kernel 4: fused = S_n*EE + (1-S_n)*HH  (fp32 out, fully coalesced)
// ---------------------------------------------------------------------------
__global__ __launch_bounds__(256) void k_blend(const unsigned short* __restrict__ ee,
                                               const unsigned short* __restrict__ hh,
                                               const float* __restrict__ S,
                                               const float* __restrict__ mm,
                                               float* __restrict__ out) {
  size_t base = ((size_t)blockIdx.x * 256 + threadIdx.x) * 8;
  int b = (int)(base >> 22);            // / (256*16384)
  int p = (int)(base & 16383);
  float mn = mm[b * 2], mx = mm[b * 2 + 1];
  float inv = 1.f / (mx - mn);
  uint4v eu = *(const uint4v*)(ee + base);
  uint4v hu = *(const uint4v*)(hh + base);
  const float* sp = S + ((size_t)b << 14) + p;
  float4v s0 = *(const float4v*)(sp);
  float4v s1 = *(const float4v*)(sp + 4);
  float sv[8];
  #pragma unroll
  for (int i = 0; i < 4; ++i) { sv[i] = s0[i]; sv[4 + i] = s1[i]; }
  float ov[8];
  #pragma unroll
  for (int i = 0; i < 4; ++i) {
    unsigned int ew = eu[i], hw = hu[i];
    float e0 = bf2f((unsigned short)(ew & 0xffffu));
    float e1 = bf2f((unsigned short)(ew >> 16));
    float h0 = bf2f((unsigned short)(hw & 0xffffu));
    float h1 = bf2f((unsigned short)(hw >> 16));
    float a0 = (sv[2 * i] - mn) * inv;
    float a1 = (sv[2 * i + 1] - mn) * inv;
    ov[2 * i]     = h0 + a0 * (e0 - h0);
    ov[2 * i + 1] = h1 + a1 * (e1 - h1);
  }
  float4v r0 = {ov[0], ov[1], ov[2], ov[3]};
  float4v r1 = {ov[4], ov[5], ov[6], ov[7]};
  *(float4v*)(out + base)     = r0;
  *(float4v*)(out + base + 4) = r1;
}

// ---------------------------------------------------------------------------
// Workspace layout (bytes):
//   0          : xcm   4 tensors bf16, 4*TSZ*2   = 268,435,456
//   268435456  : wbf   4x256x256 bf16            =     524,288
//   268959744  : eecm  bf16                      =  67,108,864
//   336068608  : hhcm  bf16                      =  67,108,864
//   403177472  : S     fp32 8x16384              =     524,288
//   403701760  : mm    fp32 8x2                  =          64
// total ~403.7 MB
// ---------------------------------------------------------------------------
extern "C" void kernel_launch(void* const* d_in, const int* in_sizes, int n_in,
                              void* d_out, int out_size, void* d_ws, size_t ws_size,
                              hipStream_t stream) {
  const float* front = (const float*)d_in[0];
  const float* back  = (const float*)d_in[1];
  // d_in[2] = mask (unused by reference)
  const float* we = (const float*)d_in[3];
  const float* be = (const float*)d_in[4];
  const float* wf = (const float*)d_in[5];
  const float* bf = (const float*)d_in[6];
  const float* wg = (const float*)d_in[7];
  const float* bg = (const float*)d_in[8];
  const float* wh = (const float*)d_in[9];
  const float* bh = (const float*)d_in[10];

  char* ws = (char*)d_ws;
  unsigned short* xcm  = (unsigned short*)(ws);
  unsigned short* wbf  = (unsigned short*)(ws + 268435456);
  unsigned short* eecm = (unsigned short*)(ws + 268959744);
  unsigned short* hhcm = (unsigned short*)(ws + 336068608);
  float*          S    = (float*)(ws + 403177472);
  float*          mm   = (float*)(ws + 403701760);
  float*          out  = (float*)d_out;

  k_prep  <<<1024,  256, 0, stream>>>(we, wf, wg, wh, wbf);
  k_stats <<<16384, 256, 0, stream>>>(front, back, xcm);
  k_gemm  <<<2048,  256, 0, stream>>>(xcm, wbf, bf, bg, be, bh, eecm, hhcm, S);
  k_minmax<<<8,     256, 0, stream>>>(S, mm);
  k_blend <<<16384, 256, 0, stream>>>(eecm, hhcm, S, mm, out);
}

// Round 2
// 712.685 us; speedup vs baseline: 1.2309x; 1.2309x over previous
//
#include <hip/hip_runtime.h>
#include <math.h>

// Problem constants: B=8, C=256, H=W=128
#define PIX 16384                       // H*W
#define TSZ ((size_t)33554432)          // 8*256*16384 elements per tensor

typedef __attribute__((ext_vector_type(8))) short  short8;   // 8 x bf16 (4 VGPRs)
typedef __attribute__((ext_vector_type(4))) float  float4v;
typedef __attribute__((ext_vector_type(4))) unsigned int uint4v;

__device__ __forceinline__ unsigned short f2bf(float x) {
  unsigned int u = __float_as_uint(x);
  u += 0x7fffu + ((u >> 16) & 1u);      // round-to-nearest-even
  return (unsigned short)(u >> 16);
}
__device__ __forceinline__ float bf2f(unsigned short h) {
  return __uint_as_float(((unsigned int)h) << 16);
}
// pack two fp32 -> (bf16(hi)<<16)|bf16(lo) via v_perm_b32
__device__ __forceinline__ unsigned int pack_bf2(float lo, float hi) {
  unsigned int ul = __float_as_uint(lo); ul += 0x7fffu + ((ul >> 16) & 1u);
  unsigned int uh = __float_as_uint(hi); uh += 0x7fffu + ((uh >> 16) & 1u);
  return __builtin_amdgcn_perm(uh, ul, 0x07060302u);  // [ul.b2,ul.b3,uh.b2,uh.b3]
}

// ---------------------------------------------------------------------------
// Kernel 0: convert the four 256x256 weight matrices to bf16.
// Conv order: 0=FF(wf), 1=GG(wg), 2=EE(we), 3=HH(wh)
// ---------------------------------------------------------------------------
__global__ __launch_bounds__(256) void k_prep(const float* __restrict__ we,
                                              const float* __restrict__ wf,
                                              const float* __restrict__ wg,
                                              const float* __restrict__ wh,
                                              unsigned short* __restrict__ wbf) {
  int idx = blockIdx.x * 256 + threadIdx.x;      // 0 .. 262143
  int which = idx >> 16, off = idx & 65535;
  const float* src = (which == 0) ? wf : (which == 1) ? wg : (which == 2) ? we : wh;
  wbf[idx] = f2bf(src[off]);
}

// ---------------------------------------------------------------------------
// Kernel 1: 7x7 patch stats (zero-padded box sums), normalization, adain.
// One block per (b, c, 16-row strip). BACK in phase 0, FRONT in phase 1;
// back's mean/sd carried in REGISTERS (same thread owns same pixels).
// Writes 4 bf16 tensors channel-major into xcm[tensor][b][c][p]:
//   0 = front_norm (FF input), 1 = back_norm (GG input),
//   2 = adain      (EE input), 3 = back cast (HH input)
// LDS design (bank-conflict audited):
//   xs  : fp32, stride 129   -> vert reads conflict-free, horiz ~2-way
//   vsp : float2 (sum,sum2), stride 131 -> b64 ops, uniform bank sweep
//   obI : u64 out staging, rotate-by-r swizzle -> <=2-way writes,
//         conflict-free scalar copy-out reads, coalesced b128 global stores
// 36.3 KB LDS -> 4 blocks/CU (50% occupancy).
// ---------------------------------------------------------------------------
__global__ __launch_bounds__(256, 4) void k_stats(const float* __restrict__ front,
                                                  const float* __restrict__ back,
                                                  unsigned short* __restrict__ xcm) {
  int blk = blockIdx.x;
  int s   = blk & 7;            // strip (16 rows)
  int c   = (blk >> 3) & 255;
  int b   = blk >> 11;
  int t   = threadIdx.x;
  int r0  = s * 16;

  __shared__ float  xs[22 * 129];
  __shared__ float2 vsp[16 * 131];
  __shared__ unsigned long long obI[16 * 64];

  size_t planeOff = ((size_t)(b * 256 + c)) * PIX;

  float meanR[8], sdR[8];       // back stats, phase0 -> phase1 carry

  #pragma unroll 1
  for (int phase = 0; phase < 2; ++phase) {     // 0 = back, 1 = front
    const float* src = (phase == 0 ? back : front) + planeOff;
    // ---- load 22 rows (3-halo, zero outside [0,128)) x 128 cols, float4 ----
    #pragma unroll
    for (int i = 0; i < 3; ++i) {
      int idx = t + i * 256;                     // 704 = 22*32 float4s
      if (idx < 704) {
        int l = idx >> 5, cv = (idx & 31) * 4;
        int g = r0 - 3 + l;
        float4v v = {0.f, 0.f, 0.f, 0.f};
        if (g >= 0 && g < 128) v = *(const float4v*)(src + g * 128 + cv);
        xs[l * 129 + cv]     = v[0];
        xs[l * 129 + cv + 1] = v[1];
        xs[l * 129 + cv + 2] = v[2];
        xs[l * 129 + cv + 3] = v[3];
      }
    }
    __syncthreads();
    // ---- vertical 7-tap sliding box sums of (x, x^2) -> float2 ----
    {
      int col = t & 127;
      int rg  = (t >> 7) * 8;                    // 8 output rows per thread
      float sm = 0.f, s2 = 0.f;
      #pragma unroll
      for (int j = 0; j < 7; ++j) { float v = xs[(rg + j) * 129 + col]; sm += v; s2 = fmaf(v, v, s2); }
      vsp[rg * 131 + col] = make_float2(sm, s2);
      #pragma unroll
      for (int o = 1; o < 8; ++o) {
        float vn = xs[(rg + o + 6) * 129 + col];
        float vo = xs[(rg + o - 1) * 129 + col];
        sm += vn - vo;
        s2 += vn * vn - vo * vo;
        vsp[(rg + o) * 131 + col] = make_float2(sm, s2);
      }
    }
    __syncthreads();
    // ---- horizontal 7-tap sliding via 14-elem register window + finalize ----
    {
      int r  = t & 15;
      int c0 = (t >> 4) * 8;                     // 8 output cols per thread
      float2 w[14];
      #pragma unroll
      for (int i = 0; i < 14; ++i) {
        int cc = c0 - 3 + i;
        float2 v = make_float2(0.f, 0.f);
        if (cc >= 0 && cc < 128) v = vsp[r * 131 + cc];
        w[i] = v;
      }
      float sm = 0.f, s2 = 0.f;
      #pragma unroll
      for (int i = 0; i < 7; ++i) { sm += w[i].x; s2 += w[i].y; }
      float nrmv[8], xv[8];
      #pragma unroll
      for (int o = 0; o < 8; ++o) {
        float mean = sm * (1.f / 49.f);
        float var  = (s2 - sm * mean) * (1.f / 48.f);   // (s2 - s^2/49)/48
        var = var > 0.f ? var : 0.f;
        float sd = __builtin_amdgcn_sqrtf(var);
        float x  = xs[(r + 3) * 129 + c0 + o];
        float nrm = (x - mean) * __builtin_amdgcn_rcpf(sd + 1e-8f);
        if (phase == 0) { meanR[o] = mean; sdR[o] = sd; }
        nrmv[o] = nrm; xv[o] = x;
        if (o < 7) { sm += w[o + 7].x - w[o].x; s2 += w[o + 7].y - w[o].y; }
      }
      #pragma unroll
      for (int op = 0; op < 4; ++op) {
        unsigned int lo32 = pack_bf2(nrmv[2 * op], nrmv[2 * op + 1]);
        float h0, h1;
        if (phase == 0) { h0 = xv[2 * op]; h1 = xv[2 * op + 1]; }
        else {
          h0 = nrmv[2 * op]     * sdR[2 * op]     + meanR[2 * op];
          h1 = nrmv[2 * op + 1] * sdR[2 * op + 1] + meanR[2 * op + 1];
        }
        unsigned int hi32 = pack_bf2(h0, h1);
        int m = (c0 >> 1) + op;                  // u32-pair column 0..63
        obI[r * 64 + ((m + r) & 63)] = ((unsigned long long)hi32 << 32) | lo32;
      }
    }
    __syncthreads();
    // ---- copy-out: de-swizzle, 2 coalesced b128 global stores/thread ----
    {
      int r  = t >> 4;
      int mg = (t & 15) * 4;
      unsigned int t0[4], t1[4];
      #pragma unroll
      for (int k2 = 0; k2 < 4; ++k2) {
        unsigned long long v = obI[r * 64 + ((mg + k2 + r) & 63)];
        t0[k2] = (unsigned int)v;
        t1[k2] = (unsigned int)(v >> 32);
      }
      size_t gb = planeOff + (size_t)(r0 + r) * 128 + (size_t)mg * 2;
      int tn0 = (phase == 0) ? 1 : 0;
      int tn1 = (phase == 0) ? 3 : 2;
      *(uint4v*)(xcm + (size_t)tn0 * TSZ + gb) = (uint4v){t0[0], t0[1], t0[2], t0[3]};
      *(uint4v*)(xcm + (size_t)tn1 * TSZ + gb) = (uint4v){t1[0], t1[1], t1[2], t1[3]};
    }
    // no barrier needed before next-phase load: it writes xs, which was last
    // read before the pre-copyout barrier; obI reads complete before each
    // thread's own global store, and horiz(P1) writes obI only after 2 more
    // barriers.
  }
}

// ---------------------------------------------------------------------------
// Kernel 2: four fused conv1x1 GEMMs per 64-pixel tile via bf16 MFMA.
// (unchanged this round — next profile will attribute its counters)
// ---------------------------------------------------------------------------
__device__ __forceinline__ void gemm_tile(const unsigned short* __restrict__ X,
                                          const unsigned short* __restrict__ Wm,
                                          int mbase, int lane, int p0,
                                          float4v acc[4][4]) {
  int col = lane & 15;
  int q   = lane >> 4;
  #pragma unroll
  for (int in = 0; in < 4; ++in)
    #pragma unroll
    for (int im = 0; im < 4; ++im)
      acc[in][im] = (float4v){0.f, 0.f, 0.f, 0.f};
  #pragma unroll 2
  for (int k0 = 0; k0 < 256; k0 += 32) {
    int kq = k0 + q * 8;
    short8 af[4];
    #pragma unroll
    for (int im = 0; im < 4; ++im)
      af[im] = *(const short8*)(Wm + (mbase + im * 16 + col) * 256 + kq);
    short8 bfr[4];
    #pragma unroll
    for (int in = 0; in < 4; ++in) {
      const unsigned short* xb = X + (size_t)kq * PIX + (p0 + in * 16 + col);
      union { short8 v; unsigned int u[4]; } bu;
      #pragma unroll
      for (int i = 0; i < 4; ++i) {
        unsigned int lo = xb[(size_t)(2 * i) * PIX];
        unsigned int hi = xb[(size_t)(2 * i + 1) * PIX];
        bu.u[i] = lo | (hi << 16);
      }
      bfr[in] = bu.v;
    }
    #pragma unroll
    for (int in = 0; in < 4; ++in)
      #pragma unroll
      for (int im = 0; im < 4; ++im)
        acc[in][im] = __builtin_amdgcn_mfma_f32_16x16x32_bf16(af[im], bfr[in], acc[in][im], 0, 0, 0);
  }
}

__global__ __launch_bounds__(256, 2) void k_gemm(const unsigned short* __restrict__ xcm,
                                                 const unsigned short* __restrict__ wbf,
                                                 const float* __restrict__ bFF,
                                                 const float* __restrict__ bGG,
                                                 const float* __restrict__ bEE,
                                                 const float* __restrict__ bHH,
                                                 unsigned short* __restrict__ eecm,
                                                 unsigned short* __restrict__ hhcm,
                                                 float* __restrict__ Sout) {
  int blk  = blockIdx.x;
  int b    = blk >> 8;
  int p0   = (blk & 255) * 64;
  int t    = threadIdx.x;
  int wv   = t >> 6;
  int lane = t & 63;
  int col  = lane & 15;
  int q    = lane >> 4;
  int mbase = wv * 64;

  __shared__ float sred[3 * 64];       // dot, |F|^2, |G|^2 per pixel
  if (t < 192) sred[t] = 0.f;
  __syncthreads();

  const unsigned short* Xb = xcm + (size_t)b * (256 * PIX);

  float4v aF[4][4], aG[4][4];

  // FF = wf * front_norm + bf ; GG = wg * back_norm + bg
  gemm_tile(Xb + 0 * TSZ, wbf + 0 * 65536, mbase, lane, p0, aF);
  gemm_tile(Xb + 1 * TSZ, wbf + 1 * 65536, mbase, lane, p0, aG);
  #pragma unroll
  for (int im = 0; im < 4; ++im) {
    float4v bvF = *(const float4v*)(bFF + mbase + im * 16 + q * 4);
    float4v bvG = *(const float4v*)(bGG + mbase + im * 16 + q * 4);
    #pragma unroll
    for (int in = 0; in < 4; ++in) { aF[in][im] += bvF; aG[in][im] += bvG; }
  }
  // cosine partials: lane-local over 16 m's, then quad shuffle, then LDS
  #pragma unroll
  for (int in = 0; in < 4; ++in) {
    float d = 0.f, nf = 0.f, ng = 0.f;
    #pragma unroll
    for (int im = 0; im < 4; ++im)
      #pragma unroll
      for (int r = 0; r < 4; ++r) {
        float f = aF[in][im][r], g = aG[in][im][r];
        d += f * g; nf += f * f; ng += g * g;
      }
    d  += __shfl_xor(d, 16);  d  += __shfl_xor(d, 32);
    nf += __shfl_xor(nf, 16); nf += __shfl_xor(nf, 32);
    ng += __shfl_xor(ng, 16); ng += __shfl_xor(ng, 32);
    if (lane < 16) {
      atomicAdd(&sred[0 * 64 + in * 16 + lane], d);
      atomicAdd(&sred[1 * 64 + in * 16 + lane], nf);
      atomicAdd(&sred[2 * 64 + in * 16 + lane], ng);
    }
  }
  // EE = we * adain + be  -> store bf16 channel-major
  gemm_tile(Xb + 2 * TSZ, wbf + 2 * 65536, mbase, lane, p0, aF);
  #pragma unroll
  for (int im = 0; im < 4; ++im) {
    float4v bv = *(const float4v*)(bEE + mbase + im * 16 + q * 4);
    #pragma unroll
    for (int in = 0; in < 4; ++in)
      #pragma unroll
      for (int r = 0; r < 4; ++r) {
        int m = mbase + im * 16 + q * 4 + r;
        eecm[((size_t)(b * 256 + m)) * PIX + p0 + in * 16 + col] = f2bf(aF[in][im][r] + bv[r]);
      }
  }
  // HH = wh * back + bh
  gemm_tile(Xb + 3 * TSZ, wbf + 3 * 65536, mbase, lane, p0, aG);
  #pragma unroll
  for (int im = 0; im < 4; ++im) {
    float4v bv = *(const float4v*)(bHH + mbase + im * 16 + q * 4);
    #pragma unroll
    for (int in = 0; in < 4; ++in)
      #pragma unroll
      for (int r = 0; r < 4; ++r) {
        int m = mbase + im * 16 + q * 4 + r;
        hhcm[((size_t)(b * 256 + m)) * PIX + p0 + in * 16 + col] = f2bf(aG[in][im][r] + bv[r]);
      }
  }
  __syncthreads();
  if (t < 64) {
    float d = sred[t], nf = sred[64 + t], ng = sred[128 + t];
    Sout[(size_t)b * PIX + p0 + t] = d / (sqrtf(nf) * sqrtf(ng));
  }
}

// ---------------------------------------------------------------------------
// Kernel 3: per-batch min/max of S (one block per batch)
// ---------------------------------------------------------------------------
__global__ __launch_bounds__(256) void k_minmax(const float* __restrict__ S,
                                                float* __restrict__ mm) {
  int b = blockIdx.x, t = threadIdx.x;
  const float* sp = S + (size_t)b * PIX;
  float mn = 3.0e38f, mx = -3.0e38f;
  for (int i = t; i < PIX; i += 256) { float v = sp[i]; mn = fminf(mn, v); mx = fmaxf(mx, v); }
  #pragma unroll
  for (int o = 32; o >= 1; o >>= 1) {
    mn = fminf(mn, __shfl_xor(mn, o));
    mx = fmaxf(mx, __shfl_xor(mx, o));
  }
  __shared__ float smn[4], smx[4];
  if ((t & 63) == 0) { smn[t >> 6] = mn; smx[t >> 6] = mx; }
  __syncthreads();
  if (t == 0) {
    mn = fminf(fminf(smn[0], smn[1]), fminf(smn[2], smn[3]));
    mx = fmaxf(fmaxf(smx[0], smx[1]), fmaxf(smx[2], smx[3]));
    mm[b * 2] = mn; mm[b * 2 + 1] = mx;
  }
}

// ---------------------------------------------------------------------------
// Kernel 4: fused = S_n*EE + (1-S_n)*HH  (fp32 out, fully coalesced)
// ---------------------------------------------------------------------------
__global__ __launch_bounds__(256) void k_blend(const unsigned short* __restrict__ ee,
                                               const unsigned short* __restrict__ hh,
                                               const float* __restrict__ S,
                                               const float* __restrict__ mm,
                                               float* __restrict__ out) {
  size_t base = ((size_t)blockIdx.x * 256 + threadIdx.x) * 8;
  int b = (int)(base >> 22);            // / (256*16384)
  int p = (int)(base & 16383);
  float mn = mm[b * 2], mx = mm[b * 2 + 1];
  float inv = 1.f / (mx - mn);
  uint4v eu = *(const uint4v*)(ee + base);
  uint4v hu = *(const uint4v*)(hh + base);
  const float* sp = S + ((size_t)b << 14) + p;
  float4v s0 = *(const float4v*)(sp);
  float4v s1 = *(const float4v*)(sp + 4);
  float sv[8];
  #pragma unroll
  for (int i = 0; i < 4; ++i) { sv[i] = s0[i]; sv[4 + i] = s1[i]; }
  float ov[8];
  #pragma unroll
  for (int i = 0; i < 4; ++i) {
    unsigned int ew = eu[i], hw = hu[i];
    float e0 = bf2f((unsigned short)(ew & 0xffffu));
    float e1 = bf2f((unsigned short)(ew >> 16));
    float h0 = bf2f((unsigned short)(hw & 0xffffu));
    float h1 = bf2f((unsigned short)(hw >> 16));
    float a0 = (sv[2 * i] - mn) * inv;
    float a1 = (sv[2 * i + 1] - mn) * inv;
    ov[2 * i]     = h0 + a0 * (e0 - h0);
    ov[2 * i + 1] = h1 + a1 * (e1 - h1);
  }
  float4v r0 = {ov[0], ov[1], ov[2], ov[3]};
  float4v r1 = {ov[4], ov[5], ov[6], ov[7]};
  *(float4v*)(out + base)     = r0;
  *(float4v*)(out + base + 4) = r1;
}

// ---------------------------------------------------------------------------
// Workspace layout (bytes):
//   0          : xcm   4 tensors bf16, 4*TSZ*2   = 268,435,456
//   268435456  : wbf   4x256x256 bf16            =     524,288
//   268959744  : eecm  bf16                      =  67,108,864
//   336068608  : hhcm  bf16                      =  67,108,864
//   403177472  : S     fp32 8x16384              =     524,288
//   403701760  : mm    fp32 8x2                  =          64
// total ~403.7 MB
// ---------------------------------------------------------------------------
extern "C" void kernel_launch(void* const* d_in, const int* in_sizes, int n_in,
                              void* d_out, int out_size, void* d_ws, size_t ws_size,
                              hipStream_t stream) {
  const float* front = (const float*)d_in[0];
  const float* back  = (const float*)d_in[1];
  // d_in[2] = mask (unused by reference)
  const float* we = (const float*)d_in[3];
  const float* be = (const float*)d_in[4];
  const float* wf = (const float*)d_in[5];
  const float* bf = (const float*)d_in[6];
  const float* wg = (const float*)d_in[7];
  const float* bg = (const float*)d_in[8];
  const float* wh = (const float*)d_in[9];
  const float* bh = (const float*)d_in[10];

  char* ws = (char*)d_ws;
  unsigned short* xcm  = (unsigned short*)(ws);
  unsigned short* wbf  = (unsigned short*)(ws + 268435456);
  unsigned short* eecm = (unsigned short*)(ws + 268959744);
  unsigned short* hhcm = (unsigned short*)(ws + 336068608);
  float*          S    = (float*)(ws + 403177472);
  float*          mm   = (float*)(ws + 403701760);
  float*          out  = (float*)d_out;

  k_prep  <<<1024,  256, 0, stream>>>(we, wf, wg, wh, wbf);
  k_stats <<<16384, 256, 0, stream>>>(front, back, xcm);
  k_gemm  <<<2048,  256, 0, stream>>>(xcm, wbf, bf, bg, be, bh, eecm, hhcm, S);
  k_minmax<<<8,     256, 0, stream>>>(S, mm);
  k_blend <<<16384, 256, 0, stream>>>(eecm, hhcm, S, mm, out);
}